// Round 1
// baseline (67.048 us; speedup 1.0000x reference)
//
#include <hip/hip_runtime.h>
#include <math.h>

#define BROWS 2097152
#define NBLOCKS 2048
#define NTHREADS_PER_BLOCK 256

constexpr float FEPS = 1e-6f;

__device__ __forceinline__ float wave_reduce_f(float v) {
#pragma unroll
    for (int off = 32; off > 0; off >>= 1) v += __shfl_down(v, off, 64);
    return v;
}

__device__ __forceinline__ double wave_reduce_d(double v) {
#pragma unroll
    for (int off = 32; off > 0; off >>= 1) v += __shfl_down(v, off, 64);
    return v;
}

// acc slots: 0..4 = loss sums for heads 0..4, 5 = softmax mask count, 6 = success count
__global__ __launch_bounds__(256) void loss_main(
    const float* __restrict__ out0, const float* __restrict__ out1,
    const float* __restrict__ out2, const float* __restrict__ out3,
    const float* __restrict__ out4, const float* __restrict__ pos_dist,
    const int* __restrict__ targets, float* __restrict__ partials,
    int nthreads_total)
{
    // pos_dist is uniform across threads -> compiler scalarizes to s_loads
    float pd[15];
#pragma unroll
    for (int j = 0; j < 15; ++j) pd[j] = pos_dist[j];

    float acc[7] = {0.f, 0.f, 0.f, 0.f, 0.f, 0.f, 0.f};

    const int tid = blockIdx.x * blockDim.x + threadIdx.x;
    for (int i = tid; i < BROWS; i += nthreads_total) {
        int t[15];
        const long tb = (long)i * 15;
#pragma unroll
        for (int j = 0; j < 15; ++j) t[j] = targets[tb + j];

        // ---- head 0: binary, pw = 1 - pd[0]
        {
            float x = out0[i];
            float p = 1.f / (1.f + expf(-x));
            p = fminf(fmaxf(p, FEPS), 1.f - FEPS);
            float pw = 1.f - pd[0];
            float om = 1.f - p;
            float term = t[0] ? logf(p) * om * om * pw
                              : logf(om) * p * p * (1.f - pw);
            acc[0] += term;
            acc[6] += (((p > 0.5f) ? 1 : 0) == t[0]) ? 1.f : 0.f;
        }

        // ---- head 1: softmax probabilities, cols 1:9, w[j] = 1 - pd[1+j]
        {
            const float4 q0 = ((const float4*)out1)[(long)i * 2 + 0];
            const float4 q1 = ((const float4*)out1)[(long)i * 2 + 1];
            float o[8] = {q0.x, q0.y, q0.z, q0.w, q1.x, q1.y, q1.z, q1.w};
            int am_gt = 0;
            bool found = false;
            float best = o[0];
            int am_o = 0;
#pragma unroll
            for (int j = 0; j < 8; ++j) {
                int g = t[1 + j];
                if (!found && g == 1) { am_gt = j; found = true; }
                if (j > 0 && o[j] > best) { best = o[j]; am_o = j; }  // first max
                if (g == 1) {
                    float w = 1.f - pd[1 + j];
                    float om = 1.f - o[j];
                    acc[1] += logf(o[j]) * om * om * w;
                    acc[5] += 1.f;
                }
            }
            acc[6] += (am_gt == am_o) ? 1.f : 0.f;
        }

        // ---- head 2: weighted BCE on logits, cols 9:13, w[j] = pd[9+j]
        {
            const float4 q = ((const float4*)out2)[i];
            float o4[4] = {q.x, q.y, q.z, q.w};
#pragma unroll
            for (int j = 0; j < 4; ++j) {
                float o = o4[j];
                int g = t[9 + j];
                float w = pd[9 + j];
                float weight = g ? (1.f - w) : w;
                float bce = fmaxf(o, 0.f) - o * (float)g + log1pf(expf(-fabsf(o)));
                acc[2] += weight * bce;
                acc[6] += (((o > 0.5f) ? 1 : 0) == g) ? 1.f : 0.f;
            }
        }

        // ---- head 3: binary, col 13, pw = 1 - pd[13]
        {
            float x = out3[i];
            float p = 1.f / (1.f + expf(-x));
            p = fminf(fmaxf(p, FEPS), 1.f - FEPS);
            float pw = 1.f - pd[13];
            float om = 1.f - p;
            float term = t[13] ? logf(p) * om * om * pw
                               : logf(om) * p * p * (1.f - pw);
            acc[3] += term;
            acc[6] += (((p > 0.5f) ? 1 : 0) == t[13]) ? 1.f : 0.f;
        }

        // ---- head 4: binary, col 14, pw = 1 - pd[14]
        {
            float x = out4[i];
            float p = 1.f / (1.f + expf(-x));
            p = fminf(fmaxf(p, FEPS), 1.f - FEPS);
            float pw = 1.f - pd[14];
            float om = 1.f - p;
            float term = t[14] ? logf(p) * om * om * pw
                               : logf(om) * p * p * (1.f - pw);
            acc[4] += term;
            acc[6] += (((p > 0.5f) ? 1 : 0) == t[14]) ? 1.f : 0.f;
        }
    }

    // ---- block reduction: wave shuffle -> LDS across 4 waves -> partials[block]
    __shared__ float sdata[4][7];
    const int lane = threadIdx.x & 63;
    const int wave = threadIdx.x >> 6;
#pragma unroll
    for (int k = 0; k < 7; ++k) {
        float v = wave_reduce_f(acc[k]);
        if (lane == 0) sdata[wave][k] = v;
    }
    __syncthreads();
    if (threadIdx.x == 0) {
#pragma unroll
        for (int k = 0; k < 7; ++k) {
            float s = sdata[0][k] + sdata[1][k] + sdata[2][k] + sdata[3][k];
            partials[(long)blockIdx.x * 8 + k] = s;
        }
    }
}

__global__ __launch_bounds__(256) void loss_final(
    const float* __restrict__ partials, int nblocks, float* __restrict__ out)
{
    double acc[7] = {0, 0, 0, 0, 0, 0, 0};
    for (int b = threadIdx.x; b < nblocks; b += NTHREADS_PER_BLOCK) {
#pragma unroll
        for (int k = 0; k < 7; ++k) acc[k] += (double)partials[(long)b * 8 + k];
    }

    __shared__ double sd[4][7];
    const int lane = threadIdx.x & 63;
    const int wave = threadIdx.x >> 6;
#pragma unroll
    for (int k = 0; k < 7; ++k) {
        double v = wave_reduce_d(acc[k]);
        if (lane == 0) sd[wave][k] = v;
    }
    __syncthreads();
    if (threadIdx.x == 0) {
        double s[7];
#pragma unroll
        for (int k = 0; k < 7; ++k) s[k] = sd[0][k] + sd[1][k] + sd[2][k] + sd[3][k];

        const double Bd = (double)BROWS;
        double l0 = -(s[0] / Bd);                       // n = B always (gt in {0,1})
        double num = s[5];
        double l1 = (num > 0.0) ? -(s[1] / fmax(num, 1.0)) : 0.0;
        double l2 = s[2] / (Bd * 4.0);                  // mean over B*4
        double l3 = -(s[3] / Bd);
        double l4 = -(s[4] / Bd);
        out[0] = (float)(l0 + l1 + l2 + l3 + l4);
        out[1] = (float)(s[6] / 8.0);                   // label_number = 8
    }
}

extern "C" void kernel_launch(void* const* d_in, const int* in_sizes, int n_in,
                              void* d_out, int out_size, void* d_ws, size_t ws_size,
                              hipStream_t stream) {
    const float* out0 = (const float*)d_in[0];
    const float* out1 = (const float*)d_in[1];
    const float* out2 = (const float*)d_in[2];
    const float* out3 = (const float*)d_in[3];
    const float* out4 = (const float*)d_in[4];
    const float* pos_dist = (const float*)d_in[5];
    const int* targets = (const int*)d_in[6];
    float* out = (float*)d_out;
    float* partials = (float*)d_ws;

    int nblocks = NBLOCKS;
    size_t need = (size_t)nblocks * 8 * sizeof(float);
    if (ws_size < need) {
        nblocks = (int)(ws_size / (8 * sizeof(float)));
        if (nblocks < 1) nblocks = 1;
    }
    const int nthreads_total = nblocks * NTHREADS_PER_BLOCK;

    loss_main<<<nblocks, NTHREADS_PER_BLOCK, 0, stream>>>(
        out0, out1, out2, out3, out4, pos_dist, targets, partials, nthreads_total);
    loss_final<<<1, NTHREADS_PER_BLOCK, 0, stream>>>(partials, nblocks, out);
}

// Round 2
// 50.500 us; speedup vs baseline: 1.3277x; 1.3277x over previous
//
#include <hip/hip_runtime.h>
#include <math.h>

#define BROWS 2097152
#define ROWS_PER_THREAD 4
#define NTHREADS_PER_BLOCK 256
#define NBLOCKS (BROWS / (ROWS_PER_THREAD * NTHREADS_PER_BLOCK))  // 2048

constexpr float FEPS = 1e-6f;

__device__ __forceinline__ float wave_reduce_f(float v) {
#pragma unroll
    for (int off = 32; off > 0; off >>= 1) v += __shfl_down(v, off, 64);
    return v;
}

__device__ __forceinline__ double wave_reduce_d(double v) {
#pragma unroll
    for (int off = 32; off > 0; off >>= 1) v += __shfl_down(v, off, 64);
    return v;
}

// acc slots: 0..4 = loss sums heads 0..4, 5 = softmax mask count, 6 = success count
__global__ __launch_bounds__(256) void loss_main(
    const float* __restrict__ out0, const float* __restrict__ out1,
    const float* __restrict__ out2, const float* __restrict__ out3,
    const float* __restrict__ out4, const float* __restrict__ pos_dist,
    const int* __restrict__ targets, float* __restrict__ partials)
{
    // uniform -> scalarized s_loads
    float pd[15];
#pragma unroll
    for (int j = 0; j < 15; ++j) pd[j] = pos_dist[j];

    const int tid = blockIdx.x * NTHREADS_PER_BLOCK + threadIdx.x;  // 0..524287

    // ---- vector loads: 4 consecutive rows per thread ----
    // targets: 4 rows x 15 ints = 60 ints = 15 int4 (base 240B-aligned)
    int4 tq[15];
    const int4* tp = (const int4*)targets + (long)tid * 15;
#pragma unroll
    for (int k = 0; k < 15; ++k) tq[k] = tp[k];
    int t[60];
#pragma unroll
    for (int k = 0; k < 15; ++k) {
        t[4 * k + 0] = tq[k].x; t[4 * k + 1] = tq[k].y;
        t[4 * k + 2] = tq[k].z; t[4 * k + 3] = tq[k].w;
    }

    const float4 a0 = ((const float4*)out0)[tid];
    const float4 a3 = ((const float4*)out3)[tid];
    const float4 a4 = ((const float4*)out4)[tid];
    float4 b1[8];
#pragma unroll
    for (int k = 0; k < 8; ++k) b1[k] = ((const float4*)out1)[(long)tid * 8 + k];
    float4 b2[4];
#pragma unroll
    for (int k = 0; k < 4; ++k) b2[k] = ((const float4*)out2)[(long)tid * 4 + k];

    const float o0v[4] = {a0.x, a0.y, a0.z, a0.w};
    const float o3v[4] = {a3.x, a3.y, a3.z, a3.w};
    const float o4v[4] = {a4.x, a4.y, a4.z, a4.w};

    float acc0 = 0.f, acc1 = 0.f, acc2 = 0.f, acc3 = 0.f, acc4 = 0.f;
    float cnt5 = 0.f, succ = 0.f;

#pragma unroll
    for (int r = 0; r < ROWS_PER_THREAD; ++r) {
        const int* tr = &t[r * 15];

        // ---- binary heads 0,3,4: select log-arg BEFORE the log (1 log, 1 exp each)
        {
            float x = o0v[r];
            float p = __builtin_amdgcn_rcpf(1.f + __expf(-x));
            p = fminf(fmaxf(p, FEPS), 1.f - FEPS);
            float om = 1.f - p;
            bool pos = tr[0] != 0;
            float larg = pos ? p : om;
            float quad = pos ? om : p;
            float coef = pos ? (1.f - pd[0]) : pd[0];
            acc0 += __logf(larg) * quad * quad * coef;
            succ += ((x > 0.f) == pos) ? 1.f : 0.f;
        }
        {
            float x = o3v[r];
            float p = __builtin_amdgcn_rcpf(1.f + __expf(-x));
            p = fminf(fmaxf(p, FEPS), 1.f - FEPS);
            float om = 1.f - p;
            bool pos = tr[13] != 0;
            float larg = pos ? p : om;
            float quad = pos ? om : p;
            float coef = pos ? (1.f - pd[13]) : pd[13];
            acc3 += __logf(larg) * quad * quad * coef;
            succ += ((x > 0.f) == pos) ? 1.f : 0.f;
        }
        {
            float x = o4v[r];
            float p = __builtin_amdgcn_rcpf(1.f + __expf(-x));
            p = fminf(fmaxf(p, FEPS), 1.f - FEPS);
            float om = 1.f - p;
            bool pos = tr[14] != 0;
            float larg = pos ? p : om;
            float quad = pos ? om : p;
            float coef = pos ? (1.f - pd[14]) : pd[14];
            acc4 += __logf(larg) * quad * quad * coef;
            succ += ((x > 0.f) == pos) ? 1.f : 0.f;
        }

        // ---- head 1: softmax probabilities (8), masked arithmetic, no branches
        {
            const float4 qa = b1[r * 2 + 0];
            const float4 qb = b1[r * 2 + 1];
            const float o[8] = {qa.x, qa.y, qa.z, qa.w, qb.x, qb.y, qb.z, qb.w};
            int am_gt = 0;
#pragma unroll
            for (int j = 7; j >= 0; --j)
                if (tr[1 + j] != 0) am_gt = j;     // first 1 (or 0 if none)
            float best = o[0];
            int am_o = 0;
#pragma unroll
            for (int j = 1; j < 8; ++j)
                if (o[j] > best) { best = o[j]; am_o = j; }  // first max
#pragma unroll
            for (int j = 0; j < 8; ++j) {
                float m = (tr[1 + j] != 0) ? 1.f : 0.f;
                float om = 1.f - o[j];
                acc1 += m * (__logf(o[j]) * om * om * (1.f - pd[1 + j]));
                cnt5 += m;
            }
            succ += (am_gt == am_o) ? 1.f : 0.f;
        }

        // ---- head 2: weighted BCE on logits (4)
        {
            const float4 q = b2[r];
            const float o2[4] = {q.x, q.y, q.z, q.w};
#pragma unroll
            for (int j = 0; j < 4; ++j) {
                float o = o2[j];
                bool g = tr[9 + j] != 0;
                float w = pd[9 + j];
                float weight = g ? (1.f - w) : w;
                float bce = fmaxf(o, 0.f) - (g ? o : 0.f)
                          + __logf(1.f + __expf(-fabsf(o)));
                acc2 += weight * bce;
                succ += ((o > 0.5f) == g) ? 1.f : 0.f;
            }
        }
    }

    // ---- block reduction
    __shared__ float sdata[4][7];
    const int lane = threadIdx.x & 63;
    const int wave = threadIdx.x >> 6;
    float accv[7] = {acc0, acc1, acc2, acc3, acc4, cnt5, succ};
#pragma unroll
    for (int k = 0; k < 7; ++k) {
        float v = wave_reduce_f(accv[k]);
        if (lane == 0) sdata[wave][k] = v;
    }
    __syncthreads();
    if (threadIdx.x == 0) {
#pragma unroll
        for (int k = 0; k < 7; ++k) {
            float s = sdata[0][k] + sdata[1][k] + sdata[2][k] + sdata[3][k];
            partials[(long)blockIdx.x * 8 + k] = s;
        }
    }
}

__global__ __launch_bounds__(256) void loss_final(
    const float* __restrict__ partials, int nblocks, float* __restrict__ out)
{
    double acc[7] = {0, 0, 0, 0, 0, 0, 0};
    for (int b = threadIdx.x; b < nblocks; b += NTHREADS_PER_BLOCK) {
#pragma unroll
        for (int k = 0; k < 7; ++k) acc[k] += (double)partials[(long)b * 8 + k];
    }

    __shared__ double sd[4][7];
    const int lane = threadIdx.x & 63;
    const int wave = threadIdx.x >> 6;
#pragma unroll
    for (int k = 0; k < 7; ++k) {
        double v = wave_reduce_d(acc[k]);
        if (lane == 0) sd[wave][k] = v;
    }
    __syncthreads();
    if (threadIdx.x == 0) {
        double s[7];
#pragma unroll
        for (int k = 0; k < 7; ++k) s[k] = sd[0][k] + sd[1][k] + sd[2][k] + sd[3][k];

        const double Bd = (double)BROWS;
        double l0 = -(s[0] / Bd);
        double num = s[5];
        double l1 = (num > 0.0) ? -(s[1] / fmax(num, 1.0)) : 0.0;
        double l2 = s[2] / (Bd * 4.0);
        double l3 = -(s[3] / Bd);
        double l4 = -(s[4] / Bd);
        out[0] = (float)(l0 + l1 + l2 + l3 + l4);
        out[1] = (float)(s[6] / 8.0);
    }
}

extern "C" void kernel_launch(void* const* d_in, const int* in_sizes, int n_in,
                              void* d_out, int out_size, void* d_ws, size_t ws_size,
                              hipStream_t stream) {
    const float* out0 = (const float*)d_in[0];
    const float* out1 = (const float*)d_in[1];
    const float* out2 = (const float*)d_in[2];
    const float* out3 = (const float*)d_in[3];
    const float* out4 = (const float*)d_in[4];
    const float* pos_dist = (const float*)d_in[5];
    const int* targets = (const int*)d_in[6];
    float* out = (float*)d_out;
    float* partials = (float*)d_ws;

    loss_main<<<NBLOCKS, NTHREADS_PER_BLOCK, 0, stream>>>(
        out0, out1, out2, out3, out4, pos_dist, targets, partials);
    loss_final<<<1, NTHREADS_PER_BLOCK, 0, stream>>>(partials, NBLOCKS, out);
}